// Round 4
// baseline (502.508 us; speedup 1.0000x reference)
//
#include <hip/hip_runtime.h>
#include <hip/hip_bf16.h>

// Problem constants
#define B_ROWS 32768
#define K_DIM  512
#define NP     1536   // packed qkv width per input

typedef __attribute__((ext_vector_type(8))) short          bf16x8;
typedef __attribute__((ext_vector_type(8))) unsigned short u16x8;
typedef __attribute__((ext_vector_type(4))) unsigned short u16x4;
typedef __attribute__((ext_vector_type(4))) float          f32x4;

static __device__ __forceinline__ unsigned short f2bf(float f) {
  __hip_bfloat16 h = __float2bfloat16(f);
  unsigned short u; __builtin_memcpy(&u, &h, 2); return u;
}
static __device__ __forceinline__ float bf2f(unsigned short u) {
  unsigned int x = ((unsigned int)u) << 16; float f; __builtin_memcpy(&f, &x, 4); return f;
}

// async global->LDS, 16B per lane. LDS dest base must be wave-uniform; HW adds lane*16B.
static __device__ __forceinline__ void gload_lds16(const void* g, void* l) {
  __builtin_amdgcn_global_load_lds(
      (const __attribute__((address_space(1))) void*)g,
      (__attribute__((address_space(3))) void*)l, 16, 0, 0);
}

// ---------------------------------------------------------------------------
// K0: pack weights to bf16 (row-major [n][k], MFMA-B-ready) + pack biases fp32
// ---------------------------------------------------------------------------
__global__ __launch_bounds__(256) void pack_kernel(
    const float* __restrict__ Wq1, const float* __restrict__ Wk1,
    const float* __restrict__ Wv1, const float* __restrict__ Wq2,
    const float* __restrict__ Wk2, const float* __restrict__ Wv2,
    const float* __restrict__ Wo1, const float* __restrict__ Wo2,
    const float* __restrict__ bq1, const float* __restrict__ bk1,
    const float* __restrict__ bv1, const float* __restrict__ bq2,
    const float* __restrict__ bk2, const float* __restrict__ bv2,
    unsigned short* __restrict__ Wp, unsigned short* __restrict__ Wl,
    unsigned short* __restrict__ Wo1b, unsigned short* __restrict__ Wo2b,
    float* __restrict__ bp, float* __restrict__ bl)
{
  const int gid = blockIdx.x * 256 + threadIdx.x;   // 524288 threads
  const int idx = gid * 4;                          // 4 floats each
  const float* src; unsigned short* dst;
  if (idx < 786432) {                               // Wp
    int n = idx >> 9, k = idx & 511;
    const float* W = (n < 512) ? (Wq1 + (size_t)n * 512)
                   : (n < 1024) ? (Wk2 + (size_t)(n - 512) * 512)
                                : (Wv2 + (size_t)(n - 1024) * 512);
    src = W + k; dst = Wp + idx;
  } else if (idx < 1572864) {                       // Wl
    int r = idx - 786432; int n = r >> 9, k = r & 511;
    const float* W = (n < 512) ? (Wk1 + (size_t)n * 512)
                   : (n < 1024) ? (Wv1 + (size_t)(n - 512) * 512)
                                : (Wq2 + (size_t)(n - 1024) * 512);
    src = W + k; dst = Wl + r;
  } else if (idx < 1835008) {                       // Wo1
    int r = idx - 1572864; src = Wo1 + r; dst = Wo1b + r;
  } else {                                          // Wo2
    int r = idx - 1835008; src = Wo2 + r; dst = Wo2b + r;
  }
  float4 v = *reinterpret_cast<const float4*>(src);
  u16x4 o; o[0] = f2bf(v.x); o[1] = f2bf(v.y); o[2] = f2bf(v.z); o[3] = f2bf(v.w);
  *reinterpret_cast<u16x4*>(dst) = o;

  if (gid < 1536) {
    int n = gid;
    bp[n] = (n < 512) ? bq1[n] : (n < 1024) ? bk2[n - 512] : bv2[n - 1024];
  } else if (gid < 3072) {
    int n = gid - 1536;
    bl[n] = (n < 512) ? bk1[n] : (n < 1024) ? bv1[n - 512] : bq2[n - 1024];
  }
}

// ---------------------------------------------------------------------------
// K0b: fp32 -> bf16 convert of the two activation matrices (once, up front).
// ---------------------------------------------------------------------------
__global__ __launch_bounds__(256) void cvt_kernel(
    const float* __restrict__ xp, const float* __restrict__ xl,
    unsigned short* __restrict__ xpb, unsigned short* __restrict__ xlb)
{
  const size_t gid = (size_t)blockIdx.x * 256 + threadIdx.x;
  size_t i = gid * 8;
  const float* src; unsigned short* dst;
  if (i < 16777216) { src = xp + i; dst = xpb + i; }
  else              { src = xl + (i - 16777216); dst = xlb + (i - 16777216); }
  float4 a = ((const float4*)src)[0];
  float4 b = ((const float4*)src)[1];
  u16x8 o;
  o[0] = f2bf(a.x); o[1] = f2bf(a.y); o[2] = f2bf(a.z); o[3] = f2bf(a.w);
  o[4] = f2bf(b.x); o[5] = f2bf(b.y); o[6] = f2bf(b.z); o[7] = f2bf(b.w);
  *(u16x8*)dst = o;
}

// ---------------------------------------------------------------------------
// gemm8p: C[m][n] = sum_k A[m][k] * W[n][k] + bias[n]
//   Deep-pipelined counted-vmcnt structure (T2+T3+T4+T5):
//   BM=256, BN=128, BK=64, 512 threads = 8 waves (4M x 2N), per-wave 64x64.
//   LDS: 3-slot ring, slot = A[256][64] (32KB) + B[128][64] (16KB) = 48KB,
//   total 144KB (dynamic). Tile t read from slot t%3; during tile t we stage
//   tile t+2 into slot (t+2)%3 == slot of t-1, whose reads finished at the
//   barrier that ended tile t-1 -> provably race-free.
//   vmcnt(6): per tile we issue 6 global_load_lds; at tile end, outstanding =
//   6 (t+2, this tile) + <=6 (t+1, last tile); vmcnt(6) retires t+1 (VMEM
//   retires in order). Never drained to 0 until the tail.
//   T2 swizzle both-sides: linear gload dest; global source fetches logical
//   k8 = (t&7) ^ (row&7); ds_read applies the same XOR -> 16 frag rows spread
//   over 8 16B-slots (2-way = free).
// ---------------------------------------------------------------------------
template<bool OUT_F32>
__global__ __launch_bounds__(512, 2)
void gemm8p(const unsigned short* __restrict__ Aptr, int lda,
            const unsigned short* __restrict__ Wb,
            const float* __restrict__ bias,
            void* __restrict__ Cptr, int ldc, int ntiles)
{
  extern __shared__ __align__(16) unsigned short lds[];   // 73728 shorts = 144 KiB
  const int SLOT = 24576, BOFF = 16384;                   // shorts

  // bijective XCD swizzle (gridDim.x % 8 == 0 by construction)
  const int nwg = gridDim.x, cpx = nwg >> 3, b0 = blockIdx.x;
  const int wk = (b0 & 7) * cpx + (b0 >> 3);
  const int mt = wk / ntiles, nt = wk - mt * ntiles;
  const int m0 = mt << 8, n0 = nt << 7;                   // BM=256, BN=128

  const int tid = threadIdx.x;
  const int lane = tid & 63, w = tid >> 6;
  const int wm = w >> 1, wn = w & 1;                      // 4M x 2N wave grid
  const int fr = lane & 15, fk = lane >> 4, frx = fr & 7;

  // staging maps: round = 8KB = 64 rows x 8 k8-chunks; thread t -> row tid>>3,
  // fetches logical chunk (tid&7)^(row&7) so phys slot (tid&7) holds swizzled data.
  const int r8 = tid >> 3;
  const int k8 = (tid & 7) ^ (r8 & 7);
  const unsigned short* Ab = Aptr + (size_t)(m0 + r8) * lda + k8 * 8;
  const unsigned short* Bb = Wb  + (size_t)(n0 + r8) * 512 + k8 * 8;
  const int ldsW = w * 512;                               // wave-uniform lane base

  // frag-read swizzled k offsets (shorts): logical chunk kc*4+fk, XOR row&7
  const int koff0 = ((0 + fk) ^ frx) * 8;
  const int koff1 = ((4 + fk) ^ frx) * 8;

  f32x4 acc[4][4] = {};

#define STAGE_A(kt, s, j) \
  gload_lds16(Ab + (size_t)(kt) * 64 + (size_t)(j) * 64 * lda, \
              &lds[(s) * SLOT + (j) * 4096 + ldsW])
#define STAGE_B(kt, s, j) \
  gload_lds16(Bb + (size_t)(kt) * 64 + (size_t)(j) * 64 * 512, \
              &lds[(s) * SLOT + BOFF + (j) * 4096 + ldsW])

  // prologue: stage tiles 0 and 1 (6 loads each), require tile 0 complete
  STAGE_A(0, 0, 0); STAGE_A(0, 0, 1); STAGE_A(0, 0, 2); STAGE_A(0, 0, 3);
  STAGE_B(0, 0, 0); STAGE_B(0, 0, 1);
  STAGE_A(1, 1, 0); STAGE_A(1, 1, 1); STAGE_A(1, 1, 2); STAGE_A(1, 1, 3);
  STAGE_B(1, 1, 0); STAGE_B(1, 1, 1);
  asm volatile("s_waitcnt vmcnt(6)" ::: "memory");
  __builtin_amdgcn_s_barrier();

  int rd = 0;
  for (int t = 0; t < 8; ++t) {
    const int As_ = rd * SLOT, Bs_ = rd * SLOT + BOFF;
    const int st  = rd ? rd - 1 : 2;                      // (t+2)%3
    const bool pre = (t < 6);

    // ---- phase 0: quadrant rows 0-31 of this wave's 64 ----
    bf16x8 bfr[4][2], afq[2][2];
#pragma unroll
    for (int ni = 0; ni < 4; ++ni) {
      const int rb = Bs_ + (wn * 64 + ni * 16 + fr) * 64;
      bfr[ni][0] = *(const bf16x8*)&lds[rb + koff0];
      bfr[ni][1] = *(const bf16x8*)&lds[rb + koff1];
    }
#pragma unroll
    for (int m2 = 0; m2 < 2; ++m2) {
      const int ra = As_ + (wm * 64 + m2 * 16 + fr) * 64;
      afq[m2][0] = *(const bf16x8*)&lds[ra + koff0];
      afq[m2][1] = *(const bf16x8*)&lds[ra + koff1];
    }
    if (pre) { STAGE_A(t + 2, st, 0); STAGE_A(t + 2, st, 1); STAGE_A(t + 2, st, 2); }
    asm volatile("s_waitcnt lgkmcnt(8)" ::: "memory");    // partial drain (12 reads issued)
    __builtin_amdgcn_s_barrier();
    asm volatile("s_waitcnt lgkmcnt(0)" ::: "memory");
    __builtin_amdgcn_sched_barrier(0);
    __builtin_amdgcn_s_setprio(1);
#pragma unroll
    for (int m2 = 0; m2 < 2; ++m2)
#pragma unroll
      for (int ni = 0; ni < 4; ++ni)
#pragma unroll
        for (int kc = 0; kc < 2; ++kc)
          acc[m2][ni] = __builtin_amdgcn_mfma_f32_16x16x32_bf16(
              afq[m2][kc], bfr[ni][kc], acc[m2][ni], 0, 0, 0);
    __builtin_amdgcn_s_setprio(0);
    __builtin_amdgcn_s_barrier();

    // ---- phase 1: quadrant rows 32-63 ----
#pragma unroll
    for (int m2 = 0; m2 < 2; ++m2) {
      const int ra = As_ + (wm * 64 + 32 + m2 * 16 + fr) * 64;
      afq[m2][0] = *(const bf16x8*)&lds[ra + koff0];
      afq[m2][1] = *(const bf16x8*)&lds[ra + koff1];
    }
    if (pre) { STAGE_A(t + 2, st, 3); STAGE_B(t + 2, st, 0); STAGE_B(t + 2, st, 1); }
    if (pre)            asm volatile("s_waitcnt vmcnt(6)" ::: "memory");
    else if (t == 6)    asm volatile("s_waitcnt vmcnt(0)" ::: "memory");
    __builtin_amdgcn_s_barrier();
    asm volatile("s_waitcnt lgkmcnt(0)" ::: "memory");
    __builtin_amdgcn_sched_barrier(0);
    __builtin_amdgcn_s_setprio(1);
#pragma unroll
    for (int m2 = 0; m2 < 2; ++m2)
#pragma unroll
      for (int ni = 0; ni < 4; ++ni)
#pragma unroll
        for (int kc = 0; kc < 2; ++kc)
          acc[2 + m2][ni] = __builtin_amdgcn_mfma_f32_16x16x32_bf16(
              afq[m2][kc], bfr[ni][kc], acc[2 + m2][ni], 0, 0, 0);
    __builtin_amdgcn_s_setprio(0);
    __builtin_amdgcn_s_barrier();

    rd = (rd + 1 == 3) ? 0 : rd + 1;
  }
#undef STAGE_A
#undef STAGE_B

  // epilogue: bias add, store. Per-frag C map: col=n+fr, row=m+fk*4+j
#pragma unroll
  for (int ni = 0; ni < 4; ++ni) {
    const int col = n0 + wn * 64 + ni * 16 + fr;
    const float bv = bias[col];
#pragma unroll
    for (int mi = 0; mi < 4; ++mi) {
      const int rbase = m0 + wm * 64 + mi * 16 + fk * 4;
#pragma unroll
      for (int j = 0; j < 4; ++j) {
        const float v = acc[mi][ni][j] + bv;
        if (OUT_F32)
          ((float*)Cptr)[(size_t)(rbase + j) * ldc + col] = v;
        else
          ((unsigned short*)Cptr)[(size_t)(rbase + j) * ldc + col] = f2bf(v);
      }
    }
  }
}

// ---------------------------------------------------------------------------
// K2: per-row head-mixing attention, both directions. 1 wave = 1 row.
// ---------------------------------------------------------------------------
__global__ __launch_bounds__(256, 4)
void attn_kernel(unsigned short* __restrict__ qkvp, unsigned short* __restrict__ qkvl)
{
  __shared__ float lds[4][1696];  // per wave: Q[8][68], K[8][68], V[8][68], ATT[64]
  const int w = threadIdx.x >> 6, lane = threadIdx.x & 63;
  const size_t r = (size_t)blockIdx.x * 4 + w;
  unsigned short* rp = qkvp + r * NP;
  unsigned short* rl = qkvl + r * NP;
  const int l8 = lane * 8;

  u16x8 q1 = *(const u16x8*)(rp + l8);
  u16x8 k2 = *(const u16x8*)(rp + 512 + l8);
  u16x8 v2 = *(const u16x8*)(rp + 1024 + l8);
  u16x8 k1 = *(const u16x8*)(rl + l8);
  u16x8 v1 = *(const u16x8*)(rl + 512 + l8);
  u16x8 q2 = *(const u16x8*)(rl + 1024 + l8);

  float* Q   = &lds[w][0];
  float* Kk  = Q + 544;
  float* V   = Kk + 544;
  float* ATT = V + 544;
  const int h = lane >> 3, e = lane & 7;
  const int sb = h * 68 + (lane & 7) * 8;

  auto stage = [&](u16x8 qv, u16x8 kv, u16x8 vv) {
#pragma unroll
    for (int j = 0; j < 8; ++j) {
      Q [sb + j] = bf2f((unsigned short)qv[j]);
      Kk[sb + j] = bf2f((unsigned short)kv[j]);
      V [sb + j] = bf2f((unsigned short)vv[j]);
    }
  };
  auto attend = [&](unsigned short* outp) {
    float s = 0.f;
#pragma unroll
    for (int d = 0; d < 64; ++d) s += Q[h * 68 + d] * Kk[e * 68 + d];
    s *= 0.125f;
    float m = fmaxf(s, __shfl_xor(s, 1, 8));
    m = fmaxf(m, __shfl_xor(m, 2, 8));
    m = fmaxf(m, __shfl_xor(m, 4, 8));
    const float p = __expf(s - m);
    float su = p;
    su += __shfl_xor(su, 1, 8); su += __shfl_xor(su, 2, 8); su += __shfl_xor(su, 4, 8);
    ATT[lane] = p / su;
    float o[8];
    const int d0 = (lane & 7) * 8;
#pragma unroll
    for (int j = 0; j < 8; ++j) {
      float a = 0.f;
#pragma unroll
      for (int e2 = 0; e2 < 8; ++e2) a += ATT[h * 8 + e2] * V[e2 * 68 + d0 + j];
      o[j] = a;
    }
    u16x8 ob;
#pragma unroll
    for (int j = 0; j < 8; ++j) ob[j] = f2bf(o[j]);
    *(u16x8*)(outp + l8) = ob;
  };

  stage(q1, k1, v1);
  attend(rp);            // direction 1 -> att1 over q1 segment
  stage(q2, k2, v2);
  attend(rl);            // direction 2 -> att2 over k1 segment
}

// ---------------------------------------------------------------------------
extern "C" void kernel_launch(void* const* d_in, const int* in_sizes, int n_in,
                              void* d_out, int out_size, void* d_ws, size_t ws_size,
                              hipStream_t stream)
{
  const float* xp  = (const float*)d_in[0];
  const float* xl  = (const float*)d_in[1];
  const float* Wq1 = (const float*)d_in[2];   const float* bq1 = (const float*)d_in[3];
  const float* Wk1 = (const float*)d_in[4];   const float* bk1 = (const float*)d_in[5];
  const float* Wv1 = (const float*)d_in[6];   const float* bv1 = (const float*)d_in[7];
  const float* Wq2 = (const float*)d_in[8];   const float* bq2 = (const float*)d_in[9];
  const float* Wk2 = (const float*)d_in[10];  const float* bk2 = (const float*)d_in[11];
  const float* Wv2 = (const float*)d_in[12];  const float* bv2 = (const float*)d_in[13];
  const float* Wo1 = (const float*)d_in[14];  const float* bo1 = (const float*)d_in[15];
  const float* Wo2 = (const float*)d_in[16];  const float* bo2 = (const float*)d_in[17];

  char* p = (char*)d_ws;
  unsigned short* Wp   = (unsigned short*)p; p += (size_t)786432 * 2;
  unsigned short* Wl   = (unsigned short*)p; p += (size_t)786432 * 2;
  unsigned short* Wo1b = (unsigned short*)p; p += (size_t)262144 * 2;
  unsigned short* Wo2b = (unsigned short*)p; p += (size_t)262144 * 2;
  float*          bp   = (float*)p;          p += (size_t)1536 * 4;
  float*          bl   = (float*)p;          p += (size_t)1536 * 4;
  unsigned short* qkvp = (unsigned short*)p; p += (size_t)B_ROWS * NP * 2;
  unsigned short* qkvl = (unsigned short*)p; p += (size_t)B_ROWS * NP * 2;
  (void)ws_size; (void)in_sizes; (void)n_in; (void)out_size;

  // bf16 activations live in d_out until the out-proj GEMMs overwrite it.
  unsigned short* xpb = (unsigned short*)d_out;
  unsigned short* xlb = xpb + (size_t)B_ROWS * 512;

  // 144 KiB dynamic LDS for gemm8p (idempotent; attribute sticks from the
  // uncaptured correctness call even if a captured call ignores it).
  const int LDSB = 147456;
  hipFuncSetAttribute((const void*)gemm8p<false>,
                      hipFuncAttributeMaxDynamicSharedMemorySize, LDSB);
  hipFuncSetAttribute((const void*)gemm8p<true>,
                      hipFuncAttributeMaxDynamicSharedMemorySize, LDSB);

  pack_kernel<<<2048, 256, 0, stream>>>(Wq1, Wk1, Wv1, Wq2, Wk2, Wv2, Wo1, Wo2,
                                        bq1, bk1, bv1, bq2, bk2, bv2,
                                        Wp, Wl, Wo1b, Wo2b, bp, bl);
  cvt_kernel<<<16384, 256, 0, stream>>>(xp, xl, xpb, xlb);

  // qkv projections: [32768 x 1536] = x @ Wpack^T + bpack  (bf16 out)
  // grid: 128 M-tiles x 12 N-tiles = 1536 (%8==0)
  gemm8p<false><<<1536, 512, LDSB, stream>>>(xpb, 512, Wp, bp, qkvp, NP, 12);
  gemm8p<false><<<1536, 512, LDSB, stream>>>(xlb, 512, Wl, bl, qkvl, NP, 12);

  // per-row attention, both directions (writes att1/att2 in place)
  attn_kernel<<<8192, 256, 0, stream>>>(qkvp, qkvl);

  // output projections -> fp32 outputs; grid 128 x 4 = 512 (%8==0)
  float* out_p = (float*)d_out;
  float* out_l = out_p + (size_t)B_ROWS * 512;
  gemm8p<true><<<512, 512, LDSB, stream>>>(qkvp, NP, Wo1b, bo1, out_p, 512, 4);
  gemm8p<true><<<512, 512, LDSB, stream>>>(qkvl, NP, Wo2b, bo2, out_l, 512, 4);
}